// Round 6
// baseline (579.430 us; speedup 1.0000x reference)
//
#include <hip/hip_runtime.h>
#include <math.h>

// Problem constants (b=2, n=4096, k=32, d0=64, d1=16, L=2, rh=16, HEADS=4)
#define BB    2
#define NN    4096
#define KK    32
#define D0    64
#define D1    16
#define D13   48
#define RHD   16
#define NHEAD 4
#define NLAYER 2
#define EPS   1e-6f
#define SCALE 0.18898223650461363f   // 1/sqrt(16 + 12)
#define ETOT  (BB*NN*KK)             // 262144 edges
#define AST   136                    // LDS A stride (bf16 elems), 272B row, 16B-aligned

typedef float  f32x4 __attribute__((ext_vector_type(4)));
typedef short  s16x8 __attribute__((ext_vector_type(8)));
#define MFMA16(a,b,c) __builtin_amdgcn_mfma_f32_16x16x32_bf16(a,b,c,0,0,0)

__device__ __forceinline__ unsigned short f2bf(float x) {
    union { float f; unsigned u; } v; v.f = x;
    unsigned r = v.u + 0x7fffu + ((v.u >> 16) & 1u);
    return (unsigned short)(r >> 16);
}
__device__ __forceinline__ float bf2f(unsigned short h) {
    union { unsigned u; float f; } v; v.u = ((unsigned)h) << 16;
    return v.f;
}
// hi + lo represents x to ~2^-17 rel
__device__ __forceinline__ void split_bf(float x, unsigned short* hi, unsigned short* lo) {
    unsigned short h = f2bf(x);
    *hi = h;
    *lo = f2bf(x - bf2f(h));
}

// 3-product split-precision MFMA: (ah+al)@(bh+bl) minus al@bl term
__device__ __forceinline__ f32x4 mm3(s16x8 ah, s16x8 al, s16x8 bh, s16x8 bl, f32x4 c) {
    c = MFMA16(ah, bh, c);
    c = MFMA16(ah, bl, c);
    c = MFMA16(al, bh, c);
    return c;
}

__device__ __forceinline__ float wred(float v) {
    #pragma unroll
    for (int o = 32; o > 0; o >>= 1) v += __shfl_xor(v, o, 64);
    return v;
}

__device__ __forceinline__ float gelu_t(float x) {
    float x3 = x * x * x;
    return 0.5f * x * (1.0f + tanhf(0.7978845608028654f * (x + 0.044715f * x3)));
}

// ---------------- geometry ----------------
__global__ void geom_kernel(const float* __restrict__ coords,
                            const int* __restrict__ nbr,
                            float* __restrict__ rhat,
                            float* __restrict__ dist) {
    int e = blockIdx.x * blockDim.x + threadIdx.x;
    if (e >= ETOT) return;
    int bn = e / KK;
    int bb = bn / NN;
    int j  = nbr[e];
    const float* cs = coords + (size_t)bn * 3;
    const float* cn = coords + ((size_t)bb * NN + j) * 3;
    float rx = cn[0] - cs[0], ry = cn[1] - cs[1], rz = cn[2] - cs[2];
    float d  = sqrtf(rx * rx + ry * ry + rz * rz);
    float iv = 1.0f / (d + EPS);
    rhat[e * 3 + 0] = rx * iv;
    rhat[e * 3 + 1] = ry * iv;
    rhat[e * 3 + 2] = rz * iv;
    dist[e] = d;
}

// ---------------- prenorm + q projections ----------------
__global__ __launch_bounds__(64) void prenorm_q_kernel(
    const float* __restrict__ f0, const float* __restrict__ f1,
    const float* __restrict__ Wq0, const float* __restrict__ Wq1,
    float* __restrict__ g0, float* __restrict__ g1,
    float* __restrict__ q0, float* __restrict__ q1) {
    int node = blockIdx.x;
    int lane = threadIdx.x;
    __shared__ float g0s[D0], g1s[D13];

    float x  = f0[(size_t)node * D0 + lane];
    float mu = wred(x) * (1.0f / D0);
    float dv = x - mu;
    float var = wred(dv * dv) * (1.0f / D0);
    float g0v = dv * rsqrtf(var + EPS);
    g0[(size_t)node * D0 + lane] = g0v;
    g0s[lane] = g0v;

    float w = (lane < D13) ? f1[(size_t)node * D13 + lane] : 0.0f;
    float t = wred(w * w);
    float rms = rsqrtf(t * (1.0f / D1) + EPS);
    if (lane < D13) {
        float g1v = w * rms;
        g1[(size_t)node * D13 + lane] = g1v;
        g1s[lane] = g1v;
    }
    __syncthreads();

    float acc = 0.0f;
    #pragma unroll
    for (int c = 0; c < D0; c++) acc += g0s[c] * Wq0[c * D0 + lane];
    q0[(size_t)node * D0 + lane] = acc;
    if (lane < D13) {
        int e = lane / 3, m = lane % 3;
        float a1 = 0.0f;
        #pragma unroll
        for (int c = 0; c < D1; c++) a1 += g1s[c * 3 + m] * Wq1[c * D1 + e];
        q1[(size_t)node * D13 + lane] = a1;
    }
}

// ---------------- weight pack values ----------------
// GEMM1 B (n in [0,128): [k0|v0], k in [0,96)): rows 0:64 h0, 64:80 dot1, 80:96 zero
__device__ __forceinline__ float B1val(int n, int k,
    const float* Wk00, const float* Wk10, const float* Wv00, const float* Wv10) {
    int nn = n & 63;
    const float* W0 = (n < 64) ? Wk00 : Wv00;
    const float* W1 = (n < 64) ? Wk10 : Wv10;
    if (k < 64) return W0[k * D0 + nn];
    if (k < 80) return W1[(k - 64) * D0 + nn];
    return 0.0f;
}
// GEMM2 B (n in [0,128): [sk|sv|hk(m=0..2)|hv(m=0..2)], k in [0,128)):
// k rows: 0:64 h0, 64:80 dot1, 80:128 h1 (m-major: k=80+m*16+c)
__device__ __forceinline__ float B2val(int n, int k,
    const float* Wk01, const float* Wk11, const float* Wk11r,
    const float* Wv01, const float* Wv11, const float* Wv11r) {
    if (n < 16) {
        if (k < 64) return Wk01[k * D1 + n];
        if (k < 80) return Wk11r[(k - 64) * D1 + n];
        return 0.0f;
    }
    if (n < 32) {
        int e = n - 16;
        if (k < 64) return Wv01[k * D1 + e];
        if (k < 80) return Wv11r[(k - 64) * D1 + e];
        return 0.0f;
    }
    if (n < 80) {
        int m = (n - 32) >> 4, e = (n - 32) & 15;
        if (k >= 80) { int mm = (k - 80) >> 4, c = (k - 80) & 15; if (mm == m) return Wk11[c * D1 + e]; }
        return 0.0f;
    }
    { int m = (n - 80) >> 4, e = (n - 80) & 15;
      if (k >= 80) { int mm = (k - 80) >> 4, c = (k - 80) & 15; if (mm == m) return Wv11[c * D1 + e]; }
      return 0.0f; }
}

// pack layout: P[((ks*NT + nt)*64 + lane)*8 + t] = val(n = nt*16 + (lane&15), k = ks*32 + (lane>>4)*8 + t)
__global__ void prep_kernel(
    const float* __restrict__ Wk00, const float* __restrict__ Wk10,
    const float* __restrict__ Wk01, const float* __restrict__ Wk11,
    const float* __restrict__ Wk11r,
    const float* __restrict__ Wv00, const float* __restrict__ Wv10,
    const float* __restrict__ Wv01, const float* __restrict__ Wv11,
    const float* __restrict__ Wv11r,
    const float* __restrict__ Rw20, const float* __restrict__ Rw21,
    unsigned short* __restrict__ B1H, unsigned short* __restrict__ B1L,
    unsigned short* __restrict__ B2H, unsigned short* __restrict__ B2L,
    unsigned short* __restrict__ R0H, unsigned short* __restrict__ R0L,
    unsigned short* __restrict__ R1H, unsigned short* __restrict__ R1L) {
    int id = blockIdx.x * 256 + threadIdx.x;
    if (id < 1536) {                       // B1: KS=3, NT=8
        int ks = id >> 9, rem = id & 511, nt = rem >> 6, lane = rem & 63;
        int li = lane & 15, quad = lane >> 4;
        #pragma unroll
        for (int t = 0; t < 8; t++) {
            float v = B1val(nt * 16 + li, ks * 32 + quad * 8 + t, Wk00, Wk10, Wv00, Wv10);
            split_bf(v, &B1H[id * 8 + t], &B1L[id * 8 + t]);
        }
    } else if (id < 3584) {                // B2: KS=4, NT=8
        int id2 = id - 1536;
        int ks = id2 >> 9, rem = id2 & 511, nt = rem >> 6, lane = rem & 63;
        int li = lane & 15, quad = lane >> 4;
        #pragma unroll
        for (int t = 0; t < 8; t++) {
            float v = B2val(nt * 16 + li, ks * 32 + quad * 8 + t,
                            Wk01, Wk11, Wk11r, Wv01, Wv11, Wv11r);
            split_bf(v, &B2H[id2 * 8 + t], &B2L[id2 * 8 + t]);
        }
    } else if (id < 3840) {                // R0: KS=1, NT=4 (K=32 padded, real K=16)
        int id2 = id - 3584;
        int nt = id2 >> 6, lane = id2 & 63;
        int li = lane & 15, quad = lane >> 4;
        #pragma unroll
        for (int t = 0; t < 8; t++) {
            int k = quad * 8 + t;
            float v = (k < 16) ? Rw20[k * D0 + nt * 16 + li] : 0.0f;
            split_bf(v, &R0H[id2 * 8 + t], &R0L[id2 * 8 + t]);
        }
    } else if (id < 3904) {                // R1: KS=1, NT=1
        int id2 = id - 3840;
        int li = id2 & 15, quad = id2 >> 4;
        #pragma unroll
        for (int t = 0; t < 8; t++) {
            int k = quad * 8 + t;
            float v = (k < 16) ? Rw21[k * D1 + li] : 0.0f;
            split_bf(v, &R1H[id2 * 8 + t], &R1L[id2 * 8 + t]);
        }
    }
}

// ---------------- fused attention: 64 edges (2 nodes) per 128-thread block ----
// wave w owns node w (rows w*32..w*32+31). Split-precision MFMA GEMMs; softmax,
// weighted sums, and output projection are wave-local.
// LDS trimmed to ~38KB (radial A-fragments + v1 live in registers) -> 4 blocks/CU.
// NOTE: no occupancy floor (R2: __launch_bounds__(...,4) caused VGPR=64 + GB-scale spills)
__global__ __launch_bounds__(128) void attn_fused_kernel(
    const float* __restrict__ g0g, const float* __restrict__ g1g,
    const int* __restrict__ nbr_idx,
    const float* __restrict__ rhatg, const float* __restrict__ distg,
    const float* __restrict__ q0g, const float* __restrict__ q1g,
    const float* __restrict__ Rw1, const float* __restrict__ Rb1,
    const unsigned short* __restrict__ B1H, const unsigned short* __restrict__ B1L,
    const unsigned short* __restrict__ B2H, const unsigned short* __restrict__ B2L,
    const unsigned short* __restrict__ R0H, const unsigned short* __restrict__ R0L,
    const unsigned short* __restrict__ R1H, const unsigned short* __restrict__ R1L,
    const float* __restrict__ Wo0, const float* __restrict__ Wo1,
    float* __restrict__ f0b, float* __restrict__ f1b) {

    int B0    = blockIdx.x * 64;       // first edge
    int node0 = blockIdx.x * 2;        // first node
    int bb    = node0 >> 12;           // / NN
    int tid   = threadIdx.x;
    int lane  = tid & 63, w = tid >> 6;      // w = wave = node-local
    int li    = lane & 15, quad = lane >> 4;

    __shared__ unsigned short AsH[64][AST], AsL[64][AST];   // 34,816 B
    __shared__ float rhts[64 * 3];   // 768
    __shared__ float dsts[64];       // 256
    __shared__ float q0s[2 * D0];    // 512
    __shared__ float q1s[2 * D13];   // 384
    __shared__ int   idxs[64];       // 256
    __shared__ float lgs[64][4];     // 1024 (logits, then softmax weights)
    __shared__ float o0s[2][D0];     // 512
    __shared__ float o1s[2][D13];    // 384

    // ---- stage meta ----
    if (tid < 64) {
        idxs[tid] = nbr_idx[B0 + tid];
        dsts[tid] = distg[B0 + tid];
        rhts[tid]       = rhatg[(size_t)B0 * 3 + tid];
        rhts[tid + 64]  = rhatg[(size_t)B0 * 3 + tid + 64];
        rhts[tid + 128] = rhatg[(size_t)B0 * 3 + tid + 128];
    }
    q0s[tid] = q0g[(size_t)node0 * D0 + tid];
    if (tid < 96) q1s[tid] = q1g[(size_t)node0 * D13 + tid];
    __syncthreads();

    int mrow0 = w * 32 + li;
    int koff  = quad * 8;

    // ---- radial A-fragments in registers (rows mrow0, mrow0+16; cols koff..koff+7) ----
    // u >= 16 (quads 2,3) are K-padding zeros. Same total gelu count as LDS version.
    s16x8 rah0, ral0, rah1, ral1;
    {
        float d0v = dsts[mrow0], d1v = dsts[mrow0 + 16];
        #pragma unroll
        for (int t = 0; t < 8; t++) {
            int u = koff + t;
            float x0 = 0.0f, x1 = 0.0f;
            if (u < 16) {
                float w1 = Rw1[u], b1 = Rb1[u];
                x0 = gelu_t(d0v * w1 + b1);
                x1 = gelu_t(d1v * w1 + b1);
            }
            unsigned short h, l;
            split_bf(x0, &h, &l); rah0[t] = (short)h; ral0[t] = (short)l;
            split_bf(x1, &h, &l); rah1[t] = (short)h; ral1[t] = (short)l;
        }
    }

    // ---- build A (hi/lo): cols 0:64 h0, 64:80 dot1, 80:128 h1 (m-major) ----
    #pragma unroll
    for (int it = 0; it < 4; it++) {               // 512 tasks (j, c8)
        int v = tid + it * 128;
        int j = v >> 3, c8 = (v & 7) * 8;
        const float* src = g0g + ((size_t)bb * NN + idxs[j]) * D0 + c8;
        float4 x = *(const float4*)src;
        float4 y = *(const float4*)(src + 4);
        split_bf(x.x, &AsH[j][c8 + 0], &AsL[j][c8 + 0]);
        split_bf(x.y, &AsH[j][c8 + 1], &AsL[j][c8 + 1]);
        split_bf(x.z, &AsH[j][c8 + 2], &AsL[j][c8 + 2]);
        split_bf(x.w, &AsH[j][c8 + 3], &AsL[j][c8 + 3]);
        split_bf(y.x, &AsH[j][c8 + 4], &AsL[j][c8 + 4]);
        split_bf(y.y, &AsH[j][c8 + 5], &AsL[j][c8 + 5]);
        split_bf(y.z, &AsH[j][c8 + 6], &AsL[j][c8 + 6]);
        split_bf(y.w, &AsH[j][c8 + 7], &AsL[j][c8 + 7]);
    }
    #pragma unroll
    for (int it = 0; it < 8; it++) {               // 1024 tasks (j, c)
        int v = tid + it * 128;
        int j = v >> 4, c = v & 15;
        const float* src = g1g + ((size_t)bb * NN + idxs[j]) * D13 + c * 3;
        float a = src[0], b = src[1], cc = src[2];
        float d = a * rhts[j * 3] + b * rhts[j * 3 + 1] + cc * rhts[j * 3 + 2];
        split_bf(d,  &AsH[j][64 + c],  &AsL[j][64 + c]);
        split_bf(a,  &AsH[j][80 + c],  &AsL[j][80 + c]);
        split_bf(b,  &AsH[j][96 + c],  &AsL[j][96 + c]);
        split_bf(cc, &AsH[j][112 + c], &AsL[j][112 + c]);
    }
    __syncthreads();

    // ---- GEMM_r: r0[j][c] / r1[j][e] via MFMA (C-layout matches main accs) ----
    f32x4 r0a[2][4], r1a[2];
    #pragma unroll
    for (int i = 0; i < 2; i++) {
        #pragma unroll
        for (int j = 0; j < 4; j++) r0a[i][j] = (f32x4){0.f, 0.f, 0.f, 0.f};
        r1a[i] = (f32x4){0.f, 0.f, 0.f, 0.f};
    }
    {
        #pragma unroll
        for (int nt = 0; nt < 4; nt++) {
            s16x8 bh = *(const s16x8*)(R0H + (nt * 64 + lane) * 8);
            s16x8 bl = *(const s16x8*)(R0L + (nt * 64 + lane) * 8);
            r0a[0][nt] = mm3(rah0, ral0, bh, bl, r0a[0][nt]);
            r0a[1][nt] = mm3(rah1, ral1, bh, bl, r0a[1][nt]);
        }
        s16x8 bh = *(const s16x8*)(R1H + lane * 8);
        s16x8 bl = *(const s16x8*)(R1L + lane * 8);
        r1a[0] = mm3(rah0, ral0, bh, bl, r1a[0]);
        r1a[1] = mm3(rah1, ral1, bh, bl, r1a[1]);
    }

    // ---- GEMM2: A[64x128] @ B2[128x128] -> sk|sv|hk|hv ----
    f32x4 acc[2][8];
    #pragma unroll
    for (int i = 0; i < 2; i++)
        #pragma unroll
        for (int j = 0; j < 8; j++) acc[i][j] = (f32x4){0.f, 0.f, 0.f, 0.f};
    #pragma unroll
    for (int ks = 0; ks < 4; ks++) {
        int k0 = ks * 32 + koff;
        s16x8 ah0 = *(const s16x8*)&AsH[mrow0][k0];
        s16x8 al0 = *(const s16x8*)&AsL[mrow0][k0];
        s16x8 ah1 = *(const s16x8*)&AsH[mrow0 + 16][k0];
        s16x8 al1 = *(const s16x8*)&AsL[mrow0 + 16][k0];
        #pragma unroll
        for (int nt = 0; nt < 8; nt++) {
            s16x8 bh = *(const s16x8*)(B2H + ((ks * 8 + nt) * 64 + lane) * 8);
            s16x8 bl = *(const s16x8*)(B2L + ((ks * 8 + nt) * 64 + lane) * 8);
            acc[0][nt] = mm3(ah0, al0, bh, bl, acc[0][nt]);
            acc[1][nt] = mm3(ah1, al1, bh, bl, acc[1][nt]);
        }
    }

    // ---- epilogue2: k1/v1 assembly; q1.k1 -> lgs; v1 stays in registers ----
    float v1r[2][3][4];
    #pragma unroll
    for (int mt = 0; mt < 2; mt++) {
        #pragma unroll
        for (int r = 0; r < 4; r++) {
            int j = w * 32 + mt * 16 + quad * 4 + r;
            float r1  = r1a[mt][r];
            float rh0 = rhts[j * 3], rh1 = rhts[j * 3 + 1], rh2 = rhts[j * 3 + 2];
            float sk = acc[mt][0][r], sv = acc[mt][1][r];
            float k1a = (sk * rh0 + acc[mt][2][r]) * r1;
            float k1b = (sk * rh1 + acc[mt][3][r]) * r1;
            float k1c = (sk * rh2 + acc[mt][4][r]) * r1;
            v1r[mt][0][r] = (sv * rh0 + acc[mt][5][r]) * r1;
            v1r[mt][1][r] = (sv * rh1 + acc[mt][6][r]) * r1;
            v1r[mt][2][r] = (sv * rh2 + acc[mt][7][r]) * r1;
            int qb = w * D13 + li * 3;
            float lc = q1s[qb] * k1a + q1s[qb + 1] * k1b + q1s[qb + 2] * k1c;
            lc += __shfl_xor(lc, 1, 4);
            lc += __shfl_xor(lc, 2, 4);
            if ((li & 3) == 0) lgs[j][li >> 2] = lc;
        }
    }
    __syncthreads();

    // ---- GEMM1: A[64x96] @ B1[96x128] -> k0|v0 ----
    #pragma unroll
    for (int i = 0; i < 2; i++)
        #pragma unroll
        for (int j = 0; j < 8; j++) acc[i][j] = (f32x4){0.f, 0.f, 0.f, 0.f};
    #pragma unroll
    for (int ks = 0; ks < 3; ks++) {
        int k0 = ks * 32 + koff;
        s16x8 ah0 = *(const s16x8*)&AsH[mrow0][k0];
        s16x8 al0 = *(const s16x8*)&AsL[mrow0][k0];
        s16x8 ah1 = *(const s16x8*)&AsH[mrow0 + 16][k0];
        s16x8 al1 = *(const s16x8*)&AsL[mrow0 + 16][k0];
        #pragma unroll
        for (int nt = 0; nt < 8; nt++) {
            s16x8 bh = *(const s16x8*)(B1H + ((ks * 8 + nt) * 64 + lane) * 8);
            s16x8 bl = *(const s16x8*)(B1L + ((ks * 8 + nt) * 64 + lane) * 8);
            acc[0][nt] = mm3(ah0, al0, bh, bl, acc[0][nt]);
            acc[1][nt] = mm3(ah1, al1, bh, bl, acc[1][nt]);
        }
    }

    // ---- epilogue1: q0.k0 logits added into lgs (v0 stays in acc registers) ----
    #pragma unroll
    for (int mt = 0; mt < 2; mt++) {
        int jb = w * 32 + mt * 16 + quad * 4;
        #pragma unroll
        for (int nt = 0; nt < 4; nt++) {
            float q0e = q0s[w * D0 + nt * 16 + li];
            float p[4];
            #pragma unroll
            for (int r = 0; r < 4; r++)
                p[r] = q0e * (acc[mt][nt][r] * r0a[mt][nt][r]);
            #pragma unroll
            for (int off = 1; off < 16; off <<= 1) {
                #pragma unroll
                for (int r = 0; r < 4; r++) p[r] += __shfl_xor(p[r], off, 16);
            }
            if (li == 0) {
                #pragma unroll
                for (int r = 0; r < 4; r++) lgs[jb + r][nt] += p[r];
            }
        }
    }
    __syncthreads();

    // ---- softmax (per node = per wave; lanes 0..3 = heads) ----
    if (lane < NHEAD) {
        int h = lane;
        float mx = -1e30f;
        for (int jn = 0; jn < KK; jn++) mx = fmaxf(mx, lgs[w * 32 + jn][h]);
        float mxs = mx * SCALE;
        float s = 0.0f;
        for (int jn = 0; jn < KK; jn++) {
            float ex = expf(lgs[w * 32 + jn][h] * SCALE - mxs);
            lgs[w * 32 + jn][h] = ex;
            s += ex;
        }
        float iv = 1.0f / s;
        for (int jn = 0; jn < KK; jn++) lgs[w * 32 + jn][h] *= iv;
    }
    __syncthreads();

    // ---- weighted sums: o0 and o1 from registers (cross-quad shfl reduce) ----
    #pragma unroll
    for (int nt = 0; nt < 4; nt++) {
        float p = 0.0f;
        #pragma unroll
        for (int mt = 0; mt < 2; mt++)
            #pragma unroll
            for (int r = 0; r < 4; r++) {
                int j = w * 32 + mt * 16 + quad * 4 + r;
                p += lgs[j][nt] * (acc[mt][nt + 4][r] * r0a[mt][nt][r]);
            }
        p += __shfl_xor(p, 16, 64);
        p += __shfl_xor(p, 32, 64);
        if (quad == 0) o0s[w][nt * 16 + li] = p;
    }
    {
        int h = li >> 2;
        #pragma unroll
        for (int m = 0; m < 3; m++) {
            float p = 0.0f;
            #pragma unroll
            for (int mt = 0; mt < 2; mt++)
                #pragma unroll
                for (int r = 0; r < 4; r++) {
                    int j = w * 32 + mt * 16 + quad * 4 + r;
                    p += lgs[j][h] * v1r[mt][m][r];
                }
            p += __shfl_xor(p, 16, 64);
            p += __shfl_xor(p, 32, 64);
            if (quad == 0) o1s[w][li * 3 + m] = p;
        }
    }
    __syncthreads();

    // ---- output projections + residual (per wave/node) ----
    {
        float a0 = 0.0f;
        #pragma unroll
        for (int e = 0; e < D0; e++) a0 += o0s[w][e] * Wo0[e * D0 + lane];
        f0b[(size_t)(node0 + w) * D0 + lane] += a0;
    }
    if (lane < D13) {
        int f = lane / 3, m = lane % 3;
        float a1 = 0.0f;
        #pragma unroll
        for (int c = 0; c < D1; c++) a1 += o1s[w][c * 3 + m] * Wo1[c * D1 + f];
        f1b[(size_t)(node0 + w) * D13 + lane] += a1;
    }
}

// ---------------- fused FFN ----------------
__global__ __launch_bounds__(256) void ffn_kernel(
    const float* __restrict__ F0w1, const float* __restrict__ F0w2,
    const float* __restrict__ F1w1, const float* __restrict__ F1w2,
    float* __restrict__ f0b, float* __restrict__ f1b) {
    int node = blockIdx.x;
    int tid  = threadIdx.x;
    __shared__ float g0s[D0], g1s[D13], ts[256], us[D13 * 4];

    if (tid < 64) {
        float x  = f0b[(size_t)node * D0 + tid];
        float mu = wred(x) * (1.0f / D0);
        float dv = x - mu;
        float var = wred(dv * dv) * (1.0f / D0);
        g0s[tid] = dv * rsqrtf(var + EPS);
    } else if (tid < 128) {
        int lane = tid - 64;
        float ww = (lane < D13) ? f1b[(size_t)node * D13 + lane] : 0.0f;
        float t = wred(ww * ww);
        float rms = rsqrtf(t * (1.0f / D1) + EPS);
        if (lane < D13) g1s[lane] = ww * rms;
    }
    __syncthreads();

    {
        float acc = 0.0f;
        #pragma unroll
        for (int c = 0; c < D0; c++) acc += g0s[c] * F0w1[c * 256 + tid];
        ts[tid] = gelu_t(acc);
    }
    if (tid < 192) {
        int e = tid / 3, m = tid % 3;
        float acc = 0.0f;
        #pragma unroll
        for (int c = 0; c < D1; c++) acc += g1s[c * 3 + m] * F1w1[c * 64 + e];
        us[tid] = acc;
    }
    __syncthreads();

    if (tid < 64) {
        int e = tid;
        float a = us[e * 3], b = us[e * 3 + 1], c = us[e * 3 + 2];
        float nrm = sqrtf(a * a + b * b + c * c);
        float gate = 1.0f / (1.0f + expf(-nrm));
        us[e * 3 + 0] *= gate;
        us[e * 3 + 1] *= gate;
        us[e * 3 + 2] *= gate;
    }
    __syncthreads();

    if (tid < 64) {
        float acc = 0.0f;
        #pragma unroll
        for (int j = 0; j < 256; j++) acc += ts[j] * F0w2[j * D0 + tid];
        f0b[(size_t)node * D0 + tid] += acc;
    } else if (tid < 112) {
        int idx = tid - 64, f = idx / 3, m = idx % 3;
        float acc = 0.0f;
        #pragma unroll
        for (int e = 0; e < 64; e++) acc += us[e * 3 + m] * F1w2[e * D1 + f];
        f1b[(size_t)node * D13 + idx] += acc;
    }
}

// ---------------- final concat ----------------
__global__ void concat_kernel(const float* __restrict__ f0b,
                              const float* __restrict__ f1b,
                              float* __restrict__ out) {
    int i = blockIdx.x * blockDim.x + threadIdx.x;
    if (i >= BB * NN * (D0 + D13)) return;
    int node = i / (D0 + D13), c = i % (D0 + D13);
    out[i] = (c < D0) ? f0b[(size_t)node * D0 + c]
                      : f1b[(size_t)node * D13 + (c - D0)];
}

extern "C" void kernel_launch(void* const* d_in, const int* in_sizes, int n_in,
                              void* d_out, int out_size, void* d_ws, size_t ws_size,
                              hipStream_t stream) {
    const float* f0     = (const float*)d_in[0];
    const float* f1     = (const float*)d_in[1];
    const float* coords = (const float*)d_in[2];
    const int*   nbr    = (const int*)d_in[3];
    const float* Wq0    = (const float*)d_in[4];
    const float* Wq1    = (const float*)d_in[5];
    const float* Wk00   = (const float*)d_in[6];
    const float* Wk10   = (const float*)d_in[7];
    const float* Wk01   = (const float*)d_in[8];
    const float* Wk11   = (const float*)d_in[9];
    const float* Wk11r  = (const float*)d_in[10];
    const float* Wv00   = (const float*)d_in[11];
    const float* Wv10   = (const float*)d_in[12];
    const float* Wv01   = (const float*)d_in[13];
    const float* Wv11   = (const float*)d_in[14];
    const float* Wv11r  = (const float*)d_in[15];
    const float* Rw1    = (const float*)d_in[16];
    const float* Rb1    = (const float*)d_in[17];
    const float* Rw20   = (const float*)d_in[18];
    const float* Rw21   = (const float*)d_in[19];
    const float* Wo0    = (const float*)d_in[20];
    const float* Wo1    = (const float*)d_in[21];
    const float* F0w1   = (const float*)d_in[22];
    const float* F0w2   = (const float*)d_in[23];
    const float* F1w1   = (const float*)d_in[24];
    const float* F1w2   = (const float*)d_in[25];
    float* out = (float*)d_out;

    int nodes = BB * NN;

    // workspace layout (~22 MB total)
    float* wf = (float*)d_ws;
    float* f0b   = wf; wf += (size_t)nodes * D0;
    float* f1b   = wf; wf += (size_t)nodes * D13;
    float* g0b   = wf; wf += (size_t)nodes * D0;
    float* g1b   = wf; wf += (size_t)nodes * D13;
    float* q0b   = wf; wf += (size_t)nodes * D0;
    float* q1b   = wf; wf += (size_t)nodes * D13;
    float* rhatb = wf; wf += (size_t)ETOT * 3;
    float* distb = wf; wf += (size_t)ETOT;
    unsigned short* wu = (unsigned short*)wf;
    unsigned short* B1H = wu; wu += 1536 * 8;
    unsigned short* B1L = wu; wu += 1536 * 8;
    unsigned short* B2H = wu; wu += 2048 * 8;
    unsigned short* B2L = wu; wu += 2048 * 8;
    unsigned short* R0H = wu; wu += 256 * 8;
    unsigned short* R0L = wu; wu += 256 * 8;
    unsigned short* R1H = wu; wu += 64 * 8;
    unsigned short* R1L = wu; wu += 64 * 8;

    geom_kernel<<<(ETOT + 255) / 256, 256, 0, stream>>>(coords, nbr, rhatb, distb);
    hipMemcpyAsync(f0b, f0, (size_t)nodes * D0 * sizeof(float),
                   hipMemcpyDeviceToDevice, stream);
    hipMemcpyAsync(f1b, f1, (size_t)nodes * D13 * sizeof(float),
                   hipMemcpyDeviceToDevice, stream);

    for (int l = 0; l < NLAYER; l++) {
        prenorm_q_kernel<<<nodes, 64, 0, stream>>>(
            f0b, f1b, Wq0 + l * D0 * D0, Wq1 + l * D1 * D1, g0b, g1b, q0b, q1b);
        prep_kernel<<<16, 256, 0, stream>>>(
            Wk00 + l * D0 * D0, Wk10 + l * D1 * D0,
            Wk01 + l * D0 * D1, Wk11 + l * D1 * D1, Wk11r + l * D1 * D1,
            Wv00 + l * D0 * D0, Wv10 + l * D1 * D0,
            Wv01 + l * D0 * D1, Wv11 + l * D1 * D1, Wv11r + l * D1 * D1,
            Rw20 + l * RHD * D0, Rw21 + l * RHD * D1,
            B1H, B1L, B2H, B2L, R0H, R0L, R1H, R1L);
        attn_fused_kernel<<<ETOT / 64, 128, 0, stream>>>(
            g0b, g1b, nbr, rhatb, distb, q0b, q1b,
            Rw1 + l * RHD, Rb1 + l * RHD,
            B1H, B1L, B2H, B2L, R0H, R0L, R1H, R1L,
            Wo0 + l * D0 * D0, Wo1 + l * D1 * D1,
            f0b, f1b);
        ffn_kernel<<<nodes, 256, 0, stream>>>(
            F0w1 + l * D0 * 256, F0w2 + l * 256 * D0,
            F1w1 + l * D1 * 64, F1w2 + l * 64 * D1,
            f0b, f1b);
    }

    concat_kernel<<<(nodes * (D0 + D13) + 255) / 256, 256, 0, stream>>>(f0b, f1b, out);
}

// Round 8
// 567.275 us; speedup vs baseline: 1.0214x; 1.0214x over previous
//
#include <hip/hip_runtime.h>
#include <math.h>

// Problem constants (b=2, n=4096, k=32, d0=64, d1=16, L=2, rh=16, HEADS=4)
#define BB    2
#define NN    4096
#define KK    32
#define D0    64
#define D1    16
#define D13   48
#define RHD   16
#define NHEAD 4
#define NLAYER 2
#define EPS   1e-6f
#define SCALE 0.18898223650461363f   // 1/sqrt(16 + 12)
#define ETOT  (BB*NN*KK)             // 262144 edges

typedef float  f32x4 __attribute__((ext_vector_type(4)));
typedef short  s16x8 __attribute__((ext_vector_type(8)));
#define MFMA16(a,b,c) __builtin_amdgcn_mfma_f32_16x16x32_bf16(a,b,c,0,0,0)

__device__ __forceinline__ unsigned short f2bf(float x) {
    union { float f; unsigned u; } v; v.f = x;
    unsigned r = v.u + 0x7fffu + ((v.u >> 16) & 1u);
    return (unsigned short)(r >> 16);
}
__device__ __forceinline__ float bf2f(unsigned short h) {
    union { unsigned u; float f; } v; v.u = ((unsigned)h) << 16;
    return v.f;
}
// hi + lo represents x to ~2^-17 rel
__device__ __forceinline__ void split_bf(float x, unsigned short* hi, unsigned short* lo) {
    unsigned short h = f2bf(x);
    *hi = h;
    *lo = f2bf(x - bf2f(h));
}

// 3-product split-precision MFMA: (ah+al)@(bh+bl) minus al@bl term
__device__ __forceinline__ f32x4 mm3(s16x8 ah, s16x8 al, s16x8 bh, s16x8 bl, f32x4 c) {
    c = MFMA16(ah, bh, c);
    c = MFMA16(ah, bl, c);
    c = MFMA16(al, bh, c);
    return c;
}

__device__ __forceinline__ float wred(float v) {
    #pragma unroll
    for (int o = 32; o > 0; o >>= 1) v += __shfl_xor(v, o, 64);
    return v;
}

__device__ __forceinline__ float gelu_t(float x) {
    float x3 = x * x * x;
    return 0.5f * x * (1.0f + tanhf(0.7978845608028654f * (x + 0.044715f * x3)));
}

// ---------------- geometry (once) ----------------
__global__ void geom_kernel(const float* __restrict__ coords,
                            const int* __restrict__ nbr,
                            float* __restrict__ rhat,
                            float* __restrict__ dist) {
    int e = blockIdx.x * blockDim.x + threadIdx.x;
    if (e >= ETOT) return;
    int bn = e / KK;
    int bb = bn / NN;
    int j  = nbr[e];
    const float* cs = coords + (size_t)bn * 3;
    const float* cn = coords + ((size_t)bb * NN + j) * 3;
    float rx = cn[0] - cs[0], ry = cn[1] - cs[1], rz = cn[2] - cs[2];
    float d  = sqrtf(rx * rx + ry * ry + rz * rz);
    float iv = 1.0f / (d + EPS);
    rhat[e * 3 + 0] = rx * iv;
    rhat[e * 3 + 1] = ry * iv;
    rhat[e * 3 + 2] = rz * iv;
    dist[e] = d;
}

// ---------------- prenorm + q projections + per-node hi/lo packs ----------------
__global__ __launch_bounds__(64) void prenorm_q_kernel(
    const float* __restrict__ f0, const float* __restrict__ f1,
    const float* __restrict__ Wq0, const float* __restrict__ Wq1,
    float* __restrict__ g1,
    float* __restrict__ q0, float* __restrict__ q1,
    unsigned short* __restrict__ g0H, unsigned short* __restrict__ g0L,
    unsigned short* __restrict__ g1mH, unsigned short* __restrict__ g1mL) {
    int node = blockIdx.x;
    int lane = threadIdx.x;
    __shared__ float g0s[D0], g1s[D13];

    float x  = f0[(size_t)node * D0 + lane];
    float mu = wred(x) * (1.0f / D0);
    float dv = x - mu;
    float var = wred(dv * dv) * (1.0f / D0);
    float g0v = dv * rsqrtf(var + EPS);
    split_bf(g0v, &g0H[(size_t)node * D0 + lane], &g0L[(size_t)node * D0 + lane]);
    g0s[lane] = g0v;

    float w = (lane < D13) ? f1[(size_t)node * D13 + lane] : 0.0f;
    float t = wred(w * w);
    float rms = rsqrtf(t * (1.0f / D1) + EPS);
    if (lane < D13) {
        float g1v = w * rms;
        g1[(size_t)node * D13 + lane] = g1v;
        g1s[lane] = g1v;
        int c = lane / 3, m = lane % 3;            // m-major pack for A cols 80..127
        split_bf(g1v, &g1mH[(size_t)node * D13 + m * 16 + c],
                      &g1mL[(size_t)node * D13 + m * 16 + c]);
    }
    __syncthreads();

    float acc = 0.0f;
    #pragma unroll
    for (int c = 0; c < D0; c++) acc += g0s[c] * Wq0[c * D0 + lane];
    q0[(size_t)node * D0 + lane] = acc;
    if (lane < D13) {
        int e = lane / 3, m = lane % 3;
        float a1 = 0.0f;
        #pragma unroll
        for (int c = 0; c < D1; c++) a1 += g1s[c * 3 + m] * Wq1[c * D1 + e];
        q1[(size_t)node * D13 + lane] = a1;
    }
}

// ---------------- per-edge precompute: dot1 + radial hidden (hi/lo) ----------------
__global__ __launch_bounds__(256) void edge_prep_kernel(
    const int* __restrict__ nbr,
    const float* __restrict__ rhatb, const float* __restrict__ distb,
    const float* __restrict__ g1b,
    const float* __restrict__ Rw1, const float* __restrict__ Rb1,
    unsigned short* __restrict__ d1H, unsigned short* __restrict__ d1L,
    unsigned short* __restrict__ rhHg, unsigned short* __restrict__ rhLg) {
    int t = blockIdx.x * 256 + threadIdx.x;     // t = e*16 + c
    int e = t >> 4, c = t & 15;
    int bn = e >> 5;            // e / KK
    int bb = bn >> 12;          // / NN
    int nj = nbr[e];
    const float* g1 = g1b + ((size_t)bb * NN + nj) * D13 + c * 3;
    float d1 = g1[0] * rhatb[e * 3] + g1[1] * rhatb[e * 3 + 1] + g1[2] * rhatb[e * 3 + 2];
    split_bf(d1, &d1H[t], &d1L[t]);
    float rh = gelu_t(distb[e] * Rw1[c] + Rb1[c]);
    split_bf(rh, &rhHg[t], &rhLg[t]);
}

// ---------------- weight pack values ----------------
// GEMM1 B (n in [0,128): [k0|v0], k in [0,96)): rows 0:64 h0, 64:80 dot1, 80:96 zero
__device__ __forceinline__ float B1val(int n, int k,
    const float* Wk00, const float* Wk10, const float* Wv00, const float* Wv10) {
    int nn = n & 63;
    const float* W0 = (n < 64) ? Wk00 : Wv00;
    const float* W1 = (n < 64) ? Wk10 : Wv10;
    if (k < 64) return W0[k * D0 + nn];
    if (k < 80) return W1[(k - 64) * D0 + nn];
    return 0.0f;
}
// GEMM2 B (n in [0,128): [sk|sv|hk(m)|hv(m)], k in [0,128)):
// k rows: 0:64 h0, 64:80 dot1, 80:128 h1 (m-major: k=80+m*16+c)
__device__ __forceinline__ float B2val(int n, int k,
    const float* Wk01, const float* Wk11, const float* Wk11r,
    const float* Wv01, const float* Wv11, const float* Wv11r) {
    if (n < 16) {
        if (k < 64) return Wk01[k * D1 + n];
        if (k < 80) return Wk11r[(k - 64) * D1 + n];
        return 0.0f;
    }
    if (n < 32) {
        int e = n - 16;
        if (k < 64) return Wv01[k * D1 + e];
        if (k < 80) return Wv11r[(k - 64) * D1 + e];
        return 0.0f;
    }
    if (n < 80) {
        int m = (n - 32) >> 4, e = (n - 32) & 15;
        if (k >= 80) { int mm = (k - 80) >> 4, c = (k - 80) & 15; if (mm == m) return Wk11[c * D1 + e]; }
        return 0.0f;
    }
    { int m = (n - 80) >> 4, e = (n - 80) & 15;
      if (k >= 80) { int mm = (k - 80) >> 4, c = (k - 80) & 15; if (mm == m) return Wv11[c * D1 + e]; }
      return 0.0f; }
}

// pack layout: P[((ks*NT + nt)*64 + lane)*8 + t] = val(n = nt*16 + (lane&15), k = ks*32 + (lane>>4)*8 + t)
__global__ void prep_kernel(
    const float* __restrict__ Wk00, const float* __restrict__ Wk10,
    const float* __restrict__ Wk01, const float* __restrict__ Wk11,
    const float* __restrict__ Wk11r,
    const float* __restrict__ Wv00, const float* __restrict__ Wv10,
    const float* __restrict__ Wv01, const float* __restrict__ Wv11,
    const float* __restrict__ Wv11r,
    const float* __restrict__ Rw20, const float* __restrict__ Rw21,
    unsigned short* __restrict__ B1H, unsigned short* __restrict__ B1L,
    unsigned short* __restrict__ B2H, unsigned short* __restrict__ B2L,
    unsigned short* __restrict__ R0H, unsigned short* __restrict__ R0L,
    unsigned short* __restrict__ R1H, unsigned short* __restrict__ R1L) {
    int id = blockIdx.x * 256 + threadIdx.x;
    if (id < 1536) {                       // B1: KS=3, NT=8
        int ks = id >> 9, rem = id & 511, nt = rem >> 6, lane = rem & 63;
        int li = lane & 15, quad = lane >> 4;
        #pragma unroll
        for (int t = 0; t < 8; t++) {
            float v = B1val(nt * 16 + li, ks * 32 + quad * 8 + t, Wk00, Wk10, Wv00, Wv10);
            split_bf(v, &B1H[id * 8 + t], &B1L[id * 8 + t]);
        }
    } else if (id < 3584) {                // B2: KS=4, NT=8
        int id2 = id - 1536;
        int ks = id2 >> 9, rem = id2 & 511, nt = rem >> 6, lane = rem & 63;
        int li = lane & 15, quad = lane >> 4;
        #pragma unroll
        for (int t = 0; t < 8; t++) {
            float v = B2val(nt * 16 + li, ks * 32 + quad * 8 + t,
                            Wk01, Wk11, Wk11r, Wv01, Wv11, Wv11r);
            split_bf(v, &B2H[id2 * 8 + t], &B2L[id2 * 8 + t]);
        }
    } else if (id < 3840) {                // R0: KS=1, NT=4 (K=32 padded, real K=16)
        int id2 = id - 3584;
        int nt = id2 >> 6, lane = id2 & 63;
        int li = lane & 15, quad = lane >> 4;
        #pragma unroll
        for (int t = 0; t < 8; t++) {
            int k = quad * 8 + t;
            float v = (k < 16) ? Rw20[k * D0 + nt * 16 + li] : 0.0f;
            split_bf(v, &R0H[id2 * 8 + t], &R0L[id2 * 8 + t]);
        }
    } else if (id < 3904) {                // R1: KS=1, NT=1
        int id2 = id - 3840;
        int li = id2 & 15, quad = id2 >> 4;
        #pragma unroll
        for (int t = 0; t < 8; t++) {
            int k = quad * 8 + t;
            float v = (k < 16) ? Rw21[k * D1 + li] : 0.0f;
            split_bf(v, &R1H[id2 * 8 + t], &R1L[id2 * 8 + t]);
        }
    }
}

// ---------------- fused attention: 64 edges (2 nodes) per 128-thread block ----
// All MFMA A-fragments load DIRECTLY from per-node/per-edge hi/lo packs in
// global (no LDS staging, no split_bf in hot path). LDS ~15 KB.
// R7 lesson: cross-LANE LDS handoffs (v1s/lgs/rhts/o0s/o1s) are a data race
// without synchronization even when wave-private — compiler may reorder.
// __syncthreads() at every handoff (2 waves/block -> s_barrier is cheap).
// NOTE: no occupancy floor (R2: __launch_bounds__(...,4) caused VGPR=64 + GB-scale spills)
__global__ __launch_bounds__(128) void attn_fused_kernel(
    const int* __restrict__ nbr_idx,
    const float* __restrict__ rhatg,
    const float* __restrict__ q0g, const float* __restrict__ q1g,
    const unsigned short* __restrict__ g0H, const unsigned short* __restrict__ g0L,
    const unsigned short* __restrict__ g1mH, const unsigned short* __restrict__ g1mL,
    const unsigned short* __restrict__ d1H, const unsigned short* __restrict__ d1L,
    const unsigned short* __restrict__ rhHg, const unsigned short* __restrict__ rhLg,
    const unsigned short* __restrict__ B1H, const unsigned short* __restrict__ B1L,
    const unsigned short* __restrict__ B2H, const unsigned short* __restrict__ B2L,
    const unsigned short* __restrict__ R0H, const unsigned short* __restrict__ R0L,
    const unsigned short* __restrict__ R1H, const unsigned short* __restrict__ R1L,
    const float* __restrict__ Wo0, const float* __restrict__ Wo1,
    float* __restrict__ f0b, float* __restrict__ f1b) {

    int B0    = blockIdx.x * 64;       // first edge
    int node0 = blockIdx.x * 2;        // first node
    int bb    = node0 >> 12;           // / NN
    int tid   = threadIdx.x;
    int lane  = tid & 63, w = tid >> 6;      // wave w owns node0+w (edges B0+w*32..+31)
    int li    = lane & 15, quad = lane >> 4;

    __shared__ float rhts[2][96];    // per-wave rhat copies
    __shared__ float lgs[64][4];     // logits -> softmax weights
    __shared__ float v1s[64][49];    // v1 (padded stride vs 4-way conflict)
    __shared__ float o0s[2][D0];
    __shared__ float o1s[2][D13];

    // rhat staging (lanes<32 write, all lanes read later)
    if (lane < 32) {
        int base = (B0 + w * 32) * 3;
        rhts[w][lane]      = rhatg[base + lane];
        rhts[w][lane + 32] = rhatg[base + lane + 32];
        rhts[w][lane + 64] = rhatg[base + lane + 64];
    }
    __syncthreads();   // (1) rhts handoff

    size_t e0 = (size_t)B0 + w * 32 + li, e1 = e0 + 16;
    size_t n0 = (size_t)bb * NN + nbr_idx[e0];
    size_t n1 = (size_t)bb * NN + nbr_idx[e1];

    int koff = quad * 8;

    // ---- radial GEMM: rh[e][u] @ R0/R1 -> r0a, r1a ----
    f32x4 r0a[2][4], r1a[2];
    #pragma unroll
    for (int i = 0; i < 2; i++) {
        #pragma unroll
        for (int j = 0; j < 4; j++) r0a[i][j] = (f32x4){0.f, 0.f, 0.f, 0.f};
        r1a[i] = (f32x4){0.f, 0.f, 0.f, 0.f};
    }
    {
        s16x8 zz = (s16x8){0,0,0,0,0,0,0,0};
        s16x8 rah0 = zz, ral0 = zz, rah1 = zz, ral1 = zz;
        if (quad < 2) {                      // K rows 16..31 are zero-padded in R packs
            rah0 = *(const s16x8*)(rhHg + e0 * 16 + koff);
            ral0 = *(const s16x8*)(rhLg + e0 * 16 + koff);
            rah1 = *(const s16x8*)(rhHg + e1 * 16 + koff);
            ral1 = *(const s16x8*)(rhLg + e1 * 16 + koff);
        }
        #pragma unroll
        for (int nt = 0; nt < 4; nt++) {
            s16x8 bh = *(const s16x8*)(R0H + (nt * 64 + lane) * 8);
            s16x8 bl = *(const s16x8*)(R0L + (nt * 64 + lane) * 8);
            r0a[0][nt] = mm3(rah0, ral0, bh, bl, r0a[0][nt]);
            r0a[1][nt] = mm3(rah1, ral1, bh, bl, r0a[1][nt]);
        }
        s16x8 bh = *(const s16x8*)(R1H + lane * 8);
        s16x8 bl = *(const s16x8*)(R1L + lane * 8);
        r1a[0] = mm3(rah0, ral0, bh, bl, r1a[0]);
        r1a[1] = mm3(rah1, ral1, bh, bl, r1a[1]);
    }

    // A-fragment pointers per ks (cols: 0-63 g0, 64-79 dot1, 80-127 g1 m-major)
    #define APTRS(ks, nb, ee, PH, PL)                                              \
        const unsigned short *PH, *PL;                                             \
        if (ks < 2) {                                                              \
            PH = g0H + (nb) * 64 + ks * 32 + koff;                                 \
            PL = g0L + (nb) * 64 + ks * 32 + koff;                                 \
        } else if (ks == 2) {                                                      \
            PH = (quad < 2) ? d1H + (ee) * 16 + quad * 8                           \
                            : g1mH + (nb) * 48 + (quad - 2) * 8;                   \
            PL = (quad < 2) ? d1L + (ee) * 16 + quad * 8                           \
                            : g1mL + (nb) * 48 + (quad - 2) * 8;                   \
        } else {                                                                   \
            PH = (quad < 2) ? g1mH + (nb) * 48 + 16 + quad * 8                     \
                            : g1mH + (nb) * 48 + 32 + (quad - 2) * 8;              \
            PL = (quad < 2) ? g1mL + (nb) * 48 + 16 + quad * 8                     \
                            : g1mL + (nb) * 48 + 32 + (quad - 2) * 8;              \
        }

    // ---- GEMM2: A[64x128] @ B2[128x128] -> sk|sv|hk|hv ----
    f32x4 acc[2][8];
    #pragma unroll
    for (int i = 0; i < 2; i++)
        #pragma unroll
        for (int j = 0; j < 8; j++) acc[i][j] = (f32x4){0.f, 0.f, 0.f, 0.f};
    #pragma unroll
    for (int ks = 0; ks < 4; ks++) {
        APTRS(ks, n0, e0, pH0, pL0)
        APTRS(ks, n1, e1, pH1, pL1)
        s16x8 ah0 = *(const s16x8*)pH0, al0 = *(const s16x8*)pL0;
        s16x8 ah1 = *(const s16x8*)pH1, al1 = *(const s16x8*)pL1;
        #pragma unroll
        for (int nt = 0; nt < 8; nt++) {
            s16x8 bh = *(const s16x8*)(B2H + ((ks * 8 + nt) * 64 + lane) * 8);
            s16x8 bl = *(const s16x8*)(B2L + ((ks * 8 + nt) * 64 + lane) * 8);
            acc[0][nt] = mm3(ah0, al0, bh, bl, acc[0][nt]);
            acc[1][nt] = mm3(ah1, al1, bh, bl, acc[1][nt]);
        }
    }

    // ---- epilogue2: k1/v1 assembly; q1.k1 -> lgs (init); v1 -> LDS ----
    {
        float q1v0 = q1g[(size_t)(node0 + w) * D13 + li * 3 + 0];
        float q1v1 = q1g[(size_t)(node0 + w) * D13 + li * 3 + 1];
        float q1v2 = q1g[(size_t)(node0 + w) * D13 + li * 3 + 2];
        #pragma unroll
        for (int mt = 0; mt < 2; mt++) {
            #pragma unroll
            for (int r = 0; r < 4; r++) {
                int jl = mt * 16 + quad * 4 + r;     // wave-local edge row
                int jj = w * 32 + jl;                // block-local row
                float r1  = r1a[mt][r];
                float rh0 = rhts[w][jl * 3], rh1 = rhts[w][jl * 3 + 1], rh2 = rhts[w][jl * 3 + 2];
                float sk = acc[mt][0][r], sv = acc[mt][1][r];
                float k1a = (sk * rh0 + acc[mt][2][r]) * r1;
                float k1b = (sk * rh1 + acc[mt][3][r]) * r1;
                float k1c = (sk * rh2 + acc[mt][4][r]) * r1;
                v1s[jj][li * 3 + 0] = (sv * rh0 + acc[mt][5][r]) * r1;
                v1s[jj][li * 3 + 1] = (sv * rh1 + acc[mt][6][r]) * r1;
                v1s[jj][li * 3 + 2] = (sv * rh2 + acc[mt][7][r]) * r1;
                float lc = q1v0 * k1a + q1v1 * k1b + q1v2 * k1c;
                lc += __shfl_xor(lc, 1, 4);
                lc += __shfl_xor(lc, 2, 4);
                if ((li & 3) == 0) lgs[jj][li >> 2] = lc;
            }
        }
    }
    __syncthreads();   // (2) lgs init / v1s handoff

    // ---- GEMM1: A[64x96] @ B1[96x128] -> k0|v0 (A cols 80-95 hit zero B rows) ----
    #pragma unroll
    for (int i = 0; i < 2; i++)
        #pragma unroll
        for (int j = 0; j < 8; j++) acc[i][j] = (f32x4){0.f, 0.f, 0.f, 0.f};
    #pragma unroll
    for (int ks = 0; ks < 3; ks++) {
        APTRS(ks, n0, e0, pH0, pL0)
        APTRS(ks, n1, e1, pH1, pL1)
        s16x8 ah0 = *(const s16x8*)pH0, al0 = *(const s16x8*)pL0;
        s16x8 ah1 = *(const s16x8*)pH1, al1 = *(const s16x8*)pL1;
        #pragma unroll
        for (int nt = 0; nt < 8; nt++) {
            s16x8 bh = *(const s16x8*)(B1H + ((ks * 8 + nt) * 64 + lane) * 8);
            s16x8 bl = *(const s16x8*)(B1L + ((ks * 8 + nt) * 64 + lane) * 8);
            acc[0][nt] = mm3(ah0, al0, bh, bl, acc[0][nt]);
            acc[1][nt] = mm3(ah1, al1, bh, bl, acc[1][nt]);
        }
    }

    // ---- epilogue1: q0.k0 logits += into lgs (v0 stays in acc registers) ----
    {
        float q0e[4];
        #pragma unroll
        for (int nt = 0; nt < 4; nt++)
            q0e[nt] = q0g[(size_t)(node0 + w) * D0 + nt * 16 + li];
        #pragma unroll
        for (int mt = 0; mt < 2; mt++) {
            int jb = w * 32 + mt * 16 + quad * 4;
            #pragma unroll
            for (int nt = 0; nt < 4; nt++) {
                float p[4];
                #pragma unroll
                for (int r = 0; r < 4; r++)
                    p[r] = q0e[nt] * (acc[mt][nt][r] * r0a[mt][nt][r]);
                #pragma unroll
                for (int off = 1; off < 16; off <<= 1) {
                    #pragma unroll
                    for (int r = 0; r < 4; r++) p[r] += __shfl_xor(p[r], off, 16);
                }
                if (li == 0) {
                    #pragma unroll
                    for (int r = 0; r < 4; r++) lgs[jb + r][nt] += p[r];
                }
            }
        }
    }
    __syncthreads();   // (3) lgs += handoff before softmax

    // ---- softmax (lanes 0..3 = heads) ----
    if (lane < NHEAD) {
        int h = lane;
        float mx = -1e30f;
        for (int jn = 0; jn < KK; jn++) mx = fmaxf(mx, lgs[w * 32 + jn][h]);
        float mxs = mx * SCALE;
        float s = 0.0f;
        for (int jn = 0; jn < KK; jn++) {
            float ex = expf(lgs[w * 32 + jn][h] * SCALE - mxs);
            lgs[w * 32 + jn][h] = ex;
            s += ex;
        }
        float iv = 1.0f / s;
        for (int jn = 0; jn < KK; jn++) lgs[w * 32 + jn][h] *= iv;
    }
    __syncthreads();   // (4) softmax weights handoff

    // ---- weighted sums: o0 from acc registers, o1 from v1s ----
    #pragma unroll
    for (int nt = 0; nt < 4; nt++) {
        float p = 0.0f;
        #pragma unroll
        for (int mt = 0; mt < 2; mt++)
            #pragma unroll
            for (int r = 0; r < 4; r++) {
                int j = w * 32 + mt * 16 + quad * 4 + r;
                p += lgs[j][nt] * (acc[mt][nt + 4][r] * r0a[mt][nt][r]);
            }
        p += __shfl_xor(p, 16, 64);
        p += __shfl_xor(p, 32, 64);
        if (quad == 0) o0s[w][nt * 16 + li] = p;
    }
    if (lane < D13) {
        int h = (lane / 3) >> 2;
        float p = 0.0f;
        #pragma unroll
        for (int jn = 0; jn < KK; jn++)
            p += lgs[w * 32 + jn][h] * v1s[w * 32 + jn][lane];
        o1s[w][lane] = p;
    }
    __syncthreads();   // (5) o0s/o1s handoff

    // ---- output projections + residual ----
    {
        float a0 = 0.0f;
        #pragma unroll
        for (int e = 0; e < D0; e++) a0 += o0s[w][e] * Wo0[e * D0 + lane];
        f0b[(size_t)(node0 + w) * D0 + lane] += a0;
    }
    if (lane < D13) {
        int f = lane / 3, m = lane % 3;
        float a1 = 0.0f;
        #pragma unroll
        for (int c = 0; c < D1; c++) a1 += o1s[w][c * 3 + m] * Wo1[c * D1 + f];
        f1b[(size_t)(node0 + w) * D13 + lane] += a1;
    }
    #undef APTRS
}

// ---------------- fused FFN ----------------
__global__ __launch_bounds__(256) void ffn_kernel(
    const float* __restrict__ F0w1, const float* __restrict__ F0w2,
    const float* __restrict__ F1w1, const float* __restrict__ F1w2,
    float* __restrict__ f0b, float* __restrict__ f1b) {
    int node = blockIdx.x;
    int tid  = threadIdx.x;
    __shared__ float g0s[D0], g1s[D13], ts[256], us[D13 * 4];

    if (tid < 64) {
        float x  = f0b[(size_t)node * D0 + tid];
        float mu = wred(x) * (1.0f / D0);
        float dv = x - mu;
        float var = wred(dv * dv) * (1.0f / D0);
        g0s[tid] = dv * rsqrtf(var + EPS);
    } else if (tid < 128) {
        int lane = tid - 64;
        float ww = (lane < D13) ? f1b[(size_t)node * D13 + lane] : 0.0f;
        float t = wred(ww * ww);
        float rms = rsqrtf(t * (1.0f / D1) + EPS);
        if (lane < D13) g1s[lane] = ww * rms;
    }
    __syncthreads();

    {
        float acc = 0.0f;
        #pragma unroll
        for (int c = 0; c < D0; c++) acc += g0s[c] * F0w1[c * 256 + tid];
        ts[tid] = gelu_t(acc);
    }
    if (tid < 192) {
        int e = tid / 3, m = tid % 3;
        float acc = 0.0f;
        #pragma unroll
        for (int c = 0; c < D1; c++) acc += g1s[c * 3 + m] * F1w1[c * 64 + e];
        us[tid] = acc;
    }
    __syncthreads();

    if (tid < 64) {
        int e = tid;
        float a = us[e * 3], b = us[e * 3 + 1], c = us[e * 3 + 2];
        float nrm = sqrtf(a * a + b * b + c * c);
        float gate = 1.0f / (1.0f + expf(-nrm));
        us[e * 3 + 0] *= gate;
        us[e * 3 + 1] *= gate;
        us[e * 3 + 2] *= gate;
    }
    __syncthreads();

    if (tid < 64) {
        float acc = 0.0f;
        #pragma unroll
        for (int j = 0; j < 256; j++) acc += ts[j] * F0w2[j * D0 + tid];
        f0b[(size_t)node * D0 + tid] += acc;
    } else if (tid < 112) {
        int idx = tid - 64, f = idx / 3, m = idx % 3;
        float acc = 0.0f;
        #pragma unroll
        for (int e = 0; e < 64; e++) acc += us[e * 3 + m] * F1w2[e * D1 + f];
        f1b[(size_t)node * D13 + idx] += acc;
    }
}

// ---------------- final concat ----------------
__global__ void concat_kernel(const float* __restrict__ f0b,
                              const float* __restrict__ f1b,
                              float* __restrict__ out) {
    int i = blockIdx.x * blockDim.x + threadIdx.x;
    if (i >= BB * NN * (D0 + D13)) return;
    int node = i / (D0 + D13), c = i % (D0 + D13);
    out[i] = (c < D0) ? f0b[(size_t)node * D0 + c]
                      : f1b[(size_t)node * D13 + (c - D0)];
}

extern "C" void kernel_launch(void* const* d_in, const int* in_sizes, int n_in,
                              void* d_out, int out_size, void* d_ws, size_t ws_size,
                              hipStream_t stream) {
    const float* f0     = (const float*)d_in[0];
    const float* f1     = (const float*)d_in[1];
    const float* coords = (const float*)d_in[2];
    const int*   nbr    = (const int*)d_in[3];
    const float* Wq0    = (const float*)d_in[4];
    const float* Wq1    = (const float*)d_in[5];
    const float* Wk00   = (const float*)d_in[6];
    const float* Wk10   = (const float*)d_in[7];
    const float* Wk01   = (const float*)d_in[8];
    const float* Wk11   = (const float*)d_in[9];
    const float* Wk11r  = (const float*)d_in[10];
    const float* Wv00   = (const float*)d_in[11];
    const float* Wv10   = (const float*)d_in[12];
    const float* Wv01   = (const float*)d_in[13];
    const float* Wv11   = (const float*)d_in[14];
    const float* Wv11r  = (const float*)d_in[15];
    const float* Rw1    = (const float*)d_in[16];
    const float* Rb1    = (const float*)d_in[17];
    const float* Rw20   = (const float*)d_in[18];
    const float* Rw21   = (const float*)d_in[19];
    const float* Wo0    = (const float*)d_in[20];
    const float* Wo1    = (const float*)d_in[21];
    const float* F0w1   = (const float*)d_in[22];
    const float* F0w2   = (const float*)d_in[23];
    const float* F1w1   = (const float*)d_in[24];
    const float* F1w2   = (const float*)d_in[25];
    float* out = (float*)d_out;

    int nodes = BB * NN;

    // workspace layout (~50 MB)
    float* wf = (float*)d_ws;
    float* f0b   = wf; wf += (size_t)nodes * D0;
    float* f1b   = wf; wf += (size_t)nodes * D13;
    float* g1b   = wf; wf += (size_t)nodes * D13;
    float* q0b   = wf; wf += (size_t)nodes * D0;
    float* q1b   = wf; wf += (size_t)nodes * D13;
    float* rhatb = wf; wf += (size_t)ETOT * 3;
    float* distb = wf; wf += (size_t)ETOT;
    unsigned short* wu = (unsigned short*)wf;
    unsigned short* g0H  = wu; wu += (size_t)nodes * D0;
    unsigned short* g0L  = wu; wu += (size_t)nodes * D0;
    unsigned short* g1mH = wu; wu += (size_t)nodes * D13;
    unsigned short* g1mL = wu; wu += (size_t)nodes * D13;
    unsigned short* d1H  = wu; wu += (size_t)ETOT * 16;
    unsigned short* d1L  = wu; wu += (size_t)ETOT * 16;
    unsigned short* rhH  = wu; wu += (size_t)ETOT * 16;
    unsigned short* rhL  = wu; wu += (size_t)ETOT * 16;
    unsigned short* B1H = wu; wu += 1536 * 8;
    unsigned short* B1L = wu; wu += 1536 * 8;
    unsigned short* B2H = wu; wu += 2048 * 8;
    unsigned short* B2L = wu; wu += 2048 * 8;
    unsigned short* R0H = wu; wu += 256 * 8;
    unsigned short* R0L = wu; wu += 256 * 8;
    unsigned short* R1H = wu; wu += 64 * 8;
    unsigned short* R1L = wu; wu += 64 * 8;

    geom_kernel<<<(ETOT + 255) / 256, 256, 0, stream>>>(coords, nbr, rhatb, distb);
    hipMemcpyAsync(f0b, f0, (size_t)nodes * D0 * sizeof(float),
                   hipMemcpyDeviceToDevice, stream);
    hipMemcpyAsync(f1b, f1, (size_t)nodes * D13 * sizeof(float),
                   hipMemcpyDeviceToDevice, stream);

    for (int l = 0; l < NLAYER; l++) {
        prenorm_q_kernel<<<nodes, 64, 0, stream>>>(
            f0b, f1b, Wq0 + l * D0 * D0, Wq1 + l * D1 * D1,
            g1b, q0b, q1b, g0H, g0L, g1mH, g1mL);
        prep_kernel<<<16, 256, 0, stream>>>(
            Wk00 + l * D0 * D0, Wk10 + l * D1 * D0,
            Wk01 + l * D0 * D1, Wk11 + l * D1 * D1, Wk11r + l * D1 * D1,
            Wv00 + l * D0 * D0, Wv10 + l * D1 * D0,
            Wv01 + l * D0 * D1, Wv11 + l * D1 * D1, Wv11r + l * D1 * D1,
            Rw20 + l * RHD * D0, Rw21 + l * RHD * D1,
            B1H, B1L, B2H, B2L, R0H, R0L, R1H, R1L);
        edge_prep_kernel<<<ETOT * 16 / 256, 256, 0, stream>>>(
            nbr, rhatb, distb, g1b, Rw1 + l * RHD, Rb1 + l * RHD,
            d1H, d1L, rhH, rhL);
        attn_fused_kernel<<<ETOT / 64, 128, 0, stream>>>(
            nbr, rhatb, q0b, q1b,
            g0H, g0L, g1mH, g1mL, d1H, d1L, rhH, rhL,
            B1H, B1L, B2H, B2L, R0H, R0L, R1H, R1L,
            Wo0 + l * D0 * D0, Wo1 + l * D1 * D1,
            f0b, f1b);
        ffn_kernel<<<nodes, 256, 0, stream>>>(
            F0w1 + l * D0 * 256, F0w2 + l * 256 * D0,
            F1w1 + l * D1 * 64, F1w2 + l * 64 * D1,
            f0b, f1b);
    }

    concat_kernel<<<(nodes * (D0 + D13) + 255) / 256, 256, 0, stream>>>(f0b, f1b, out);
}

// Round 9
// 522.730 us; speedup vs baseline: 1.1085x; 1.0852x over previous
//
#include <hip/hip_runtime.h>
#include <math.h>

// Problem constants (b=2, n=4096, k=32, d0=64, d1=16, L=2, rh=16, HEADS=4)
#define BB    2
#define NN    4096
#define KK    32
#define D0    64
#define D1    16
#define D13   48
#define RHD   16
#define NHEAD 4
#define NLAYER 2
#define EPS   1e-6f
#define SCALE 0.18898223650461363f   // 1/sqrt(16 + 12)
#define ETOT  (BB*NN*KK)             // 262144 edges

typedef float  f32x4 __attribute__((ext_vector_type(4)));
typedef short  s16x8 __attribute__((ext_vector_type(8)));
#define MFMA16(a,b,c) __builtin_amdgcn_mfma_f32_16x16x32_bf16(a,b,c,0,0,0)

__device__ __forceinline__ unsigned short f2bf(float x) {
    union { float f; unsigned u; } v; v.f = x;
    unsigned r = v.u + 0x7fffu + ((v.u >> 16) & 1u);
    return (unsigned short)(r >> 16);
}
__device__ __forceinline__ float bf2f(unsigned short h) {
    union { unsigned u; float f; } v; v.u = ((unsigned)h) << 16;
    return v.f;
}
// hi + lo represents x to ~2^-17 rel
__device__ __forceinline__ void split_bf(float x, unsigned short* hi, unsigned short* lo) {
    unsigned short h = f2bf(x);
    *hi = h;
    *lo = f2bf(x - bf2f(h));
}

// 3-product split-precision MFMA: (ah+al)@(bh+bl) minus al@bl term
__device__ __forceinline__ f32x4 mm3(s16x8 ah, s16x8 al, s16x8 bh, s16x8 bl, f32x4 c) {
    c = MFMA16(ah, bh, c);
    c = MFMA16(ah, bl, c);
    c = MFMA16(al, bh, c);
    return c;
}

__device__ __forceinline__ float wred(float v) {
    #pragma unroll
    for (int o = 32; o > 0; o >>= 1) v += __shfl_xor(v, o, 64);
    return v;
}

__device__ __forceinline__ float gelu_t(float x) {
    float x3 = x * x * x;
    return 0.5f * x * (1.0f + tanhf(0.7978845608028654f * (x + 0.044715f * x3)));
}

// ---------------- geometry (once) ----------------
__global__ void geom_kernel(const float* __restrict__ coords,
                            const int* __restrict__ nbr,
                            float* __restrict__ rhat,
                            float* __restrict__ dist) {
    int e = blockIdx.x * blockDim.x + threadIdx.x;
    if (e >= ETOT) return;
    int bn = e / KK;
    int bb = bn / NN;
    int j  = nbr[e];
    const float* cs = coords + (size_t)bn * 3;
    const float* cn = coords + ((size_t)bb * NN + j) * 3;
    float rx = cn[0] - cs[0], ry = cn[1] - cs[1], rz = cn[2] - cs[2];
    float d  = sqrtf(rx * rx + ry * ry + rz * rz);
    float iv = 1.0f / (d + EPS);
    rhat[e * 3 + 0] = rx * iv;
    rhat[e * 3 + 1] = ry * iv;
    rhat[e * 3 + 2] = rz * iv;
    dist[e] = d;
}

// ---------------- prenorm + q projections + per-node hi/lo packs ----------------
__global__ __launch_bounds__(64) void prenorm_q_kernel(
    const float* __restrict__ f0, const float* __restrict__ f1,
    const float* __restrict__ Wq0, const float* __restrict__ Wq1,
    float* __restrict__ g1,
    float* __restrict__ q0, float* __restrict__ q1,
    unsigned short* __restrict__ g0H, unsigned short* __restrict__ g0L,
    unsigned short* __restrict__ g1mH, unsigned short* __restrict__ g1mL) {
    int node = blockIdx.x;
    int lane = threadIdx.x;
    __shared__ float g0s[D0], g1s[D13];

    float x  = f0[(size_t)node * D0 + lane];
    float mu = wred(x) * (1.0f / D0);
    float dv = x - mu;
    float var = wred(dv * dv) * (1.0f / D0);
    float g0v = dv * rsqrtf(var + EPS);
    split_bf(g0v, &g0H[(size_t)node * D0 + lane], &g0L[(size_t)node * D0 + lane]);
    g0s[lane] = g0v;

    float w = (lane < D13) ? f1[(size_t)node * D13 + lane] : 0.0f;
    float t = wred(w * w);
    float rms = rsqrtf(t * (1.0f / D1) + EPS);
    if (lane < D13) {
        float g1v = w * rms;
        g1[(size_t)node * D13 + lane] = g1v;
        g1s[lane] = g1v;
        int c = lane / 3, m = lane % 3;            // m-major pack for A cols 80..127
        split_bf(g1v, &g1mH[(size_t)node * D13 + m * 16 + c],
                      &g1mL[(size_t)node * D13 + m * 16 + c]);
    }
    __syncthreads();

    float acc = 0.0f;
    #pragma unroll
    for (int c = 0; c < D0; c++) acc += g0s[c] * Wq0[c * D0 + lane];
    q0[(size_t)node * D0 + lane] = acc;
    if (lane < D13) {
        int e = lane / 3, m = lane % 3;
        float a1 = 0.0f;
        #pragma unroll
        for (int c = 0; c < D1; c++) a1 += g1s[c * 3 + m] * Wq1[c * D1 + e];
        q1[(size_t)node * D13 + lane] = a1;
    }
}

// ---------------- per-edge precompute: dot1 + radial hidden (hi/lo) ----------------
__global__ __launch_bounds__(256) void edge_prep_kernel(
    const int* __restrict__ nbr,
    const float* __restrict__ rhatb, const float* __restrict__ distb,
    const float* __restrict__ g1b,
    const float* __restrict__ Rw1, const float* __restrict__ Rb1,
    unsigned short* __restrict__ d1H, unsigned short* __restrict__ d1L,
    unsigned short* __restrict__ rhHg, unsigned short* __restrict__ rhLg) {
    int t = blockIdx.x * 256 + threadIdx.x;     // t = e*16 + c
    int e = t >> 4, c = t & 15;
    int bn = e >> 5;            // e / KK
    int bb = bn >> 12;          // / NN
    int nj = nbr[e];
    const float* g1 = g1b + ((size_t)bb * NN + nj) * D13 + c * 3;
    float d1 = g1[0] * rhatb[e * 3] + g1[1] * rhatb[e * 3 + 1] + g1[2] * rhatb[e * 3 + 2];
    split_bf(d1, &d1H[t], &d1L[t]);
    float rh = gelu_t(distb[e] * Rw1[c] + Rb1[c]);
    split_bf(rh, &rhHg[t], &rhLg[t]);
}

// ---------------- weight pack values ----------------
// GEMM1 B (n in [0,128): [k0|v0], k in [0,96)): rows 0:64 h0, 64:80 dot1, 80:96 zero
__device__ __forceinline__ float B1val(int n, int k,
    const float* Wk00, const float* Wk10, const float* Wv00, const float* Wv10) {
    int nn = n & 63;
    const float* W0 = (n < 64) ? Wk00 : Wv00;
    const float* W1 = (n < 64) ? Wk10 : Wv10;
    if (k < 64) return W0[k * D0 + nn];
    if (k < 80) return W1[(k - 64) * D0 + nn];
    return 0.0f;
}
// GEMM2 B (n in [0,128): [sk|sv|hk(m)|hv(m)], k in [0,128)):
// k rows: 0:64 h0, 64:80 dot1, 80:128 h1 (m-major: k=80+m*16+c)
__device__ __forceinline__ float B2val(int n, int k,
    const float* Wk01, const float* Wk11, const float* Wk11r,
    const float* Wv01, const float* Wv11, const float* Wv11r) {
    if (n < 16) {
        if (k < 64) return Wk01[k * D1 + n];
        if (k < 80) return Wk11r[(k - 64) * D1 + n];
        return 0.0f;
    }
    if (n < 32) {
        int e = n - 16;
        if (k < 64) return Wv01[k * D1 + e];
        if (k < 80) return Wv11r[(k - 64) * D1 + e];
        return 0.0f;
    }
    if (n < 80) {
        int m = (n - 32) >> 4, e = (n - 32) & 15;
        if (k >= 80) { int mm = (k - 80) >> 4, c = (k - 80) & 15; if (mm == m) return Wk11[c * D1 + e]; }
        return 0.0f;
    }
    { int m = (n - 80) >> 4, e = (n - 80) & 15;
      if (k >= 80) { int mm = (k - 80) >> 4, c = (k - 80) & 15; if (mm == m) return Wv11[c * D1 + e]; }
      return 0.0f; }
}

// pack layout: P[((ks*NT + nt)*64 + lane)*8 + t] = val(n = nt*16 + (lane&15), k = ks*32 + (lane>>4)*8 + t)
__global__ void prep_kernel(
    const float* __restrict__ Wk00, const float* __restrict__ Wk10,
    const float* __restrict__ Wk01, const float* __restrict__ Wk11,
    const float* __restrict__ Wk11r,
    const float* __restrict__ Wv00, const float* __restrict__ Wv10,
    const float* __restrict__ Wv01, const float* __restrict__ Wv11,
    const float* __restrict__ Wv11r,
    const float* __restrict__ Rw20, const float* __restrict__ Rw21,
    unsigned short* __restrict__ B1H, unsigned short* __restrict__ B1L,
    unsigned short* __restrict__ B2H, unsigned short* __restrict__ B2L,
    unsigned short* __restrict__ R0H, unsigned short* __restrict__ R0L,
    unsigned short* __restrict__ R1H, unsigned short* __restrict__ R1L) {
    int id = blockIdx.x * 256 + threadIdx.x;
    if (id < 1536) {                       // B1: KS=3, NT=8
        int ks = id >> 9, rem = id & 511, nt = rem >> 6, lane = rem & 63;
        int li = lane & 15, quad = lane >> 4;
        #pragma unroll
        for (int t = 0; t < 8; t++) {
            float v = B1val(nt * 16 + li, ks * 32 + quad * 8 + t, Wk00, Wk10, Wv00, Wv10);
            split_bf(v, &B1H[id * 8 + t], &B1L[id * 8 + t]);
        }
    } else if (id < 3584) {                // B2: KS=4, NT=8
        int id2 = id - 1536;
        int ks = id2 >> 9, rem = id2 & 511, nt = rem >> 6, lane = rem & 63;
        int li = lane & 15, quad = lane >> 4;
        #pragma unroll
        for (int t = 0; t < 8; t++) {
            float v = B2val(nt * 16 + li, ks * 32 + quad * 8 + t,
                            Wk01, Wk11, Wk11r, Wv01, Wv11, Wv11r);
            split_bf(v, &B2H[id2 * 8 + t], &B2L[id2 * 8 + t]);
        }
    } else if (id < 3840) {                // R0: KS=1, NT=4 (K=32 padded, real K=16)
        int id2 = id - 3584;
        int nt = id2 >> 6, lane = id2 & 63;
        int li = lane & 15, quad = lane >> 4;
        #pragma unroll
        for (int t = 0; t < 8; t++) {
            int k = quad * 8 + t;
            float v = (k < 16) ? Rw20[k * D0 + nt * 16 + li] : 0.0f;
            split_bf(v, &R0H[id2 * 8 + t], &R0L[id2 * 8 + t]);
        }
    } else if (id < 3904) {                // R1: KS=1, NT=1
        int id2 = id - 3840;
        int li = id2 & 15, quad = id2 >> 4;
        #pragma unroll
        for (int t = 0; t < 8; t++) {
            int k = quad * 8 + t;
            float v = (k < 16) ? Rw21[k * D1 + li] : 0.0f;
            split_bf(v, &R1H[id2 * 8 + t], &R1L[id2 * 8 + t]);
        }
    }
}

// ---------------- fused attention: 64 edges (2 nodes) per 128-thread block ----
// R9: GEMM1+GEMM2 merged into ONE K-loop (A fragments loaded once, ~30
// independent global loads in flight per iteration), fused single lgs write,
// parallel 32-lane softmax. Barriers at every cross-lane LDS handoff (R7 race
// lesson). LDS ~15 KB.
// NOTE: no occupancy floor (R2: __launch_bounds__(...,4) caused VGPR=64 + GB-scale spills)
__global__ __launch_bounds__(128) void attn_fused_kernel(
    const int* __restrict__ nbr_idx,
    const float* __restrict__ rhatg,
    const float* __restrict__ q0g, const float* __restrict__ q1g,
    const unsigned short* __restrict__ g0H, const unsigned short* __restrict__ g0L,
    const unsigned short* __restrict__ g1mH, const unsigned short* __restrict__ g1mL,
    const unsigned short* __restrict__ d1H, const unsigned short* __restrict__ d1L,
    const unsigned short* __restrict__ rhHg, const unsigned short* __restrict__ rhLg,
    const unsigned short* __restrict__ B1H, const unsigned short* __restrict__ B1L,
    const unsigned short* __restrict__ B2H, const unsigned short* __restrict__ B2L,
    const unsigned short* __restrict__ R0H, const unsigned short* __restrict__ R0L,
    const unsigned short* __restrict__ R1H, const unsigned short* __restrict__ R1L,
    const float* __restrict__ Wo0, const float* __restrict__ Wo1,
    float* __restrict__ f0b, float* __restrict__ f1b) {

    int B0    = blockIdx.x * 64;       // first edge
    int node0 = blockIdx.x * 2;        // first node
    int bb    = node0 >> 12;           // / NN
    int tid   = threadIdx.x;
    int lane  = tid & 63, w = tid >> 6;      // wave w owns node0+w (edges B0+w*32..+31)
    int li    = lane & 15, quad = lane >> 4;

    __shared__ float rhts[2][96];    // per-wave rhat copies
    __shared__ float lgs[64][4];     // logits -> softmax weights
    __shared__ float v1s[64][49];    // v1 (padded stride vs 4-way conflict)
    __shared__ float o0s[2][D0];
    __shared__ float o1s[2][D13];

    // rhat staging (lanes<32 write, all lanes read later)
    if (lane < 32) {
        int base = (B0 + w * 32) * 3;
        rhts[w][lane]      = rhatg[base + lane];
        rhts[w][lane + 32] = rhatg[base + lane + 32];
        rhts[w][lane + 64] = rhatg[base + lane + 64];
    }
    __syncthreads();   // (1) rhts handoff

    size_t e0 = (size_t)B0 + w * 32 + li, e1 = e0 + 16;
    size_t n0 = (size_t)bb * NN + nbr_idx[e0];
    size_t n1 = (size_t)bb * NN + nbr_idx[e1];

    int koff = quad * 8;

    // ---- radial GEMM: rh[e][u] @ R0/R1 -> r0a, r1a ----
    f32x4 r0a[2][4], r1a[2];
    #pragma unroll
    for (int i = 0; i < 2; i++) {
        #pragma unroll
        for (int j = 0; j < 4; j++) r0a[i][j] = (f32x4){0.f, 0.f, 0.f, 0.f};
        r1a[i] = (f32x4){0.f, 0.f, 0.f, 0.f};
    }
    {
        s16x8 zz = (s16x8){0,0,0,0,0,0,0,0};
        s16x8 rah0 = zz, ral0 = zz, rah1 = zz, ral1 = zz;
        if (quad < 2) {                      // K rows 16..31 are zero-padded in R packs
            rah0 = *(const s16x8*)(rhHg + e0 * 16 + koff);
            ral0 = *(const s16x8*)(rhLg + e0 * 16 + koff);
            rah1 = *(const s16x8*)(rhHg + e1 * 16 + koff);
            ral1 = *(const s16x8*)(rhLg + e1 * 16 + koff);
        }
        #pragma unroll
        for (int nt = 0; nt < 4; nt++) {
            s16x8 bh = *(const s16x8*)(R0H + (nt * 64 + lane) * 8);
            s16x8 bl = *(const s16x8*)(R0L + (nt * 64 + lane) * 8);
            r0a[0][nt] = mm3(rah0, ral0, bh, bl, r0a[0][nt]);
            r0a[1][nt] = mm3(rah1, ral1, bh, bl, r0a[1][nt]);
        }
        s16x8 bh = *(const s16x8*)(R1H + lane * 8);
        s16x8 bl = *(const s16x8*)(R1L + lane * 8);
        r1a[0] = mm3(rah0, ral0, bh, bl, r1a[0]);
        r1a[1] = mm3(rah1, ral1, bh, bl, r1a[1]);
    }

    // A-fragment pointers per ks (cols: 0-63 g0, 64-79 dot1, 80-127 g1 m-major)
    #define APTRS(ks, nb, ee, PH, PL)                                              \
        const unsigned short *PH, *PL;                                             \
        if (ks < 2) {                                                              \
            PH = g0H + (nb) * 64 + ks * 32 + koff;                                 \
            PL = g0L + (nb) * 64 + ks * 32 + koff;                                 \
        } else if (ks == 2) {                                                      \
            PH = (quad < 2) ? d1H + (ee) * 16 + quad * 8                           \
                            : g1mH + (nb) * 48 + (quad - 2) * 8;                   \
            PL = (quad < 2) ? d1L + (ee) * 16 + quad * 8                           \
                            : g1mL + (nb) * 48 + (quad - 2) * 8;                   \
        } else {                                                                   \
            PH = (quad < 2) ? g1mH + (nb) * 48 + 16 + quad * 8                     \
                            : g1mH + (nb) * 48 + 32 + (quad - 2) * 8;              \
            PL = (quad < 2) ? g1mL + (nb) * 48 + 16 + quad * 8                     \
                            : g1mL + (nb) * 48 + 32 + (quad - 2) * 8;              \
        }

    // ---- combined GEMM1+GEMM2 K-loop: A loaded ONCE per ks ----
    f32x4 acc1[2][8], acc2[2][8];
    #pragma unroll
    for (int i = 0; i < 2; i++)
        #pragma unroll
        for (int j = 0; j < 8; j++) {
            acc1[i][j] = (f32x4){0.f, 0.f, 0.f, 0.f};
            acc2[i][j] = (f32x4){0.f, 0.f, 0.f, 0.f};
        }
    #pragma unroll
    for (int ks = 0; ks < 4; ks++) {
        APTRS(ks, n0, e0, pH0, pL0)
        APTRS(ks, n1, e1, pH1, pL1)
        s16x8 ah0 = *(const s16x8*)pH0, al0 = *(const s16x8*)pL0;
        s16x8 ah1 = *(const s16x8*)pH1, al1 = *(const s16x8*)pL1;
        #pragma unroll
        for (int nt = 0; nt < 8; nt++) {
            s16x8 bh = *(const s16x8*)(B2H + ((ks * 8 + nt) * 64 + lane) * 8);
            s16x8 bl = *(const s16x8*)(B2L + ((ks * 8 + nt) * 64 + lane) * 8);
            acc2[0][nt] = mm3(ah0, al0, bh, bl, acc2[0][nt]);
            acc2[1][nt] = mm3(ah1, al1, bh, bl, acc2[1][nt]);
        }
        if (ks < 3) {
            #pragma unroll
            for (int nt = 0; nt < 8; nt++) {
                s16x8 bh = *(const s16x8*)(B1H + ((ks * 8 + nt) * 64 + lane) * 8);
                s16x8 bl = *(const s16x8*)(B1L + ((ks * 8 + nt) * 64 + lane) * 8);
                acc1[0][nt] = mm3(ah0, al0, bh, bl, acc1[0][nt]);
                acc1[1][nt] = mm3(ah1, al1, bh, bl, acc1[1][nt]);
            }
        }
    }

    // ---- fused epilogue: k1/v1 assembly, v1 -> LDS, single lgs write ----
    {
        float q1v0 = q1g[(size_t)(node0 + w) * D13 + li * 3 + 0];
        float q1v1 = q1g[(size_t)(node0 + w) * D13 + li * 3 + 1];
        float q1v2 = q1g[(size_t)(node0 + w) * D13 + li * 3 + 2];
        float q0e[4];
        #pragma unroll
        for (int nt = 0; nt < 4; nt++)
            q0e[nt] = q0g[(size_t)(node0 + w) * D0 + nt * 16 + li];

        #pragma unroll
        for (int mt = 0; mt < 2; mt++) {
            // q0.k0 head sums (16-lane reduce; result valid in all lanes)
            float p0[4][4];
            #pragma unroll
            for (int nt = 0; nt < 4; nt++)
                #pragma unroll
                for (int r = 0; r < 4; r++)
                    p0[nt][r] = q0e[nt] * (acc1[mt][nt][r] * r0a[mt][nt][r]);
            #pragma unroll
            for (int off = 1; off < 16; off <<= 1) {
                #pragma unroll
                for (int nt = 0; nt < 4; nt++)
                    #pragma unroll
                    for (int r = 0; r < 4; r++)
                        p0[nt][r] += __shfl_xor(p0[nt][r], off, 16);
            }
            #pragma unroll
            for (int r = 0; r < 4; r++) {
                int jl = mt * 16 + quad * 4 + r;     // wave-local edge row
                int jj = w * 32 + jl;                // block-local row
                float r1  = r1a[mt][r];
                float rh0 = rhts[w][jl * 3], rh1 = rhts[w][jl * 3 + 1], rh2 = rhts[w][jl * 3 + 2];
                float sk = acc2[mt][0][r], sv = acc2[mt][1][r];
                float k1a = (sk * rh0 + acc2[mt][2][r]) * r1;
                float k1b = (sk * rh1 + acc2[mt][3][r]) * r1;
                float k1c = (sk * rh2 + acc2[mt][4][r]) * r1;
                v1s[jj][li * 3 + 0] = (sv * rh0 + acc2[mt][5][r]) * r1;
                v1s[jj][li * 3 + 1] = (sv * rh1 + acc2[mt][6][r]) * r1;
                v1s[jj][li * 3 + 2] = (sv * rh2 + acc2[mt][7][r]) * r1;
                float lc = q1v0 * k1a + q1v1 * k1b + q1v2 * k1c;
                lc += __shfl_xor(lc, 1, 4);
                lc += __shfl_xor(lc, 2, 4);
                if ((li & 3) == 0) {
                    int h = li >> 2;
                    float l0 = (h == 0) ? p0[0][r] : (h == 1) ? p0[1][r]
                             : (h == 2) ? p0[2][r] : p0[3][r];
                    lgs[jj][h] = lc + l0;
                }
            }
        }
    }
    __syncthreads();   // (2) lgs / v1s handoff

    // ---- parallel softmax: lanes 0..31 own one edge each (4 heads in regs) ----
    if (lane < 32) {
        float4 l4 = *(const float4*)&lgs[w * 32 + lane][0];
        l4.x *= SCALE; l4.y *= SCALE; l4.z *= SCALE; l4.w *= SCALE;
        float4 mx = l4;
        #pragma unroll
        for (int off = 1; off < 32; off <<= 1) {
            mx.x = fmaxf(mx.x, __shfl_xor(mx.x, off, 32));
            mx.y = fmaxf(mx.y, __shfl_xor(mx.y, off, 32));
            mx.z = fmaxf(mx.z, __shfl_xor(mx.z, off, 32));
            mx.w = fmaxf(mx.w, __shfl_xor(mx.w, off, 32));
        }
        float4 ex;
        ex.x = expf(l4.x - mx.x); ex.y = expf(l4.y - mx.y);
        ex.z = expf(l4.z - mx.z); ex.w = expf(l4.w - mx.w);
        float4 s = ex;
        #pragma unroll
        for (int off = 1; off < 32; off <<= 1) {
            s.x += __shfl_xor(s.x, off, 32);
            s.y += __shfl_xor(s.y, off, 32);
            s.z += __shfl_xor(s.z, off, 32);
            s.w += __shfl_xor(s.w, off, 32);
        }
        ex.x /= s.x; ex.y /= s.y; ex.z /= s.z; ex.w /= s.w;
        *(float4*)&lgs[w * 32 + lane][0] = ex;
    }
    __syncthreads();   // (3) softmax weights handoff

    // ---- weighted sums: o0 from acc1 registers, o1 from v1s ----
    #pragma unroll
    for (int nt = 0; nt < 4; nt++) {
        float p = 0.0f;
        #pragma unroll
        for (int mt = 0; mt < 2; mt++)
            #pragma unroll
            for (int r = 0; r < 4; r++) {
                int j = w * 32 + mt * 16 + quad * 4 + r;
                p += lgs[j][nt] * (acc1[mt][nt + 4][r] * r0a[mt][nt][r]);
            }
        p += __shfl_xor(p, 16, 64);
        p += __shfl_xor(p, 32, 64);
        if (quad == 0) o0s[w][nt * 16 + li] = p;
    }
    if (lane < D13) {
        int h = (lane / 3) >> 2;
        float p = 0.0f;
        #pragma unroll
        for (int jn = 0; jn < KK; jn++)
            p += lgs[w * 32 + jn][h] * v1s[w * 32 + jn][lane];
        o1s[w][lane] = p;
    }
    __syncthreads();   // (4) o0s/o1s handoff

    // ---- output projections + residual ----
    {
        float a0 = 0.0f;
        #pragma unroll
        for (int e = 0; e < D0; e++) a0 += o0s[w][e] * Wo0[e * D0 + lane];
        f0b[(size_t)(node0 + w) * D0 + lane] += a0;
    }
    if (lane < D13) {
        int f = lane / 3, m = lane % 3;
        float a1 = 0.0f;
        #pragma unroll
        for (int c = 0; c < D1; c++) a1 += o1s[w][c * 3 + m] * Wo1[c * D1 + f];
        f1b[(size_t)(node0 + w) * D13 + lane] += a1;
    }
    #undef APTRS
}

// ---------------- fused FFN ----------------
__global__ __launch_bounds__(256) void ffn_kernel(
    const float* __restrict__ F0w1, const float* __restrict__ F0w2,
    const float* __restrict__ F1w1, const float* __restrict__ F1w2,
    float* __restrict__ f0b, float* __restrict__ f1b) {
    int node = blockIdx.x;
    int tid  = threadIdx.x;
    __shared__ float g0s[D0], g1s[D13], ts[256], us[D13 * 4];

    if (tid < 64) {
        float x  = f0b[(size_t)node * D0 + tid];
        float mu = wred(x) * (1.0f / D0);
        float dv = x - mu;
        float var = wred(dv * dv) * (1.0f / D0);
        g0s[tid] = dv * rsqrtf(var + EPS);
    } else if (tid < 128) {
        int lane = tid - 64;
        float ww = (lane < D13) ? f1b[(size_t)node * D13 + lane] : 0.0f;
        float t = wred(ww * ww);
        float rms = rsqrtf(t * (1.0f / D1) + EPS);
        if (lane < D13) g1s[lane] = ww * rms;
    }
    __syncthreads();

    {
        float acc = 0.0f;
        #pragma unroll
        for (int c = 0; c < D0; c++) acc += g0s[c] * F0w1[c * 256 + tid];
        ts[tid] = gelu_t(acc);
    }
    if (tid < 192) {
        int e = tid / 3, m = tid % 3;
        float acc = 0.0f;
        #pragma unroll
        for (int c = 0; c < D1; c++) acc += g1s[c * 3 + m] * F1w1[c * 64 + e];
        us[tid] = acc;
    }
    __syncthreads();

    if (tid < 64) {
        int e = tid;
        float a = us[e * 3], b = us[e * 3 + 1], c = us[e * 3 + 2];
        float nrm = sqrtf(a * a + b * b + c * c);
        float gate = 1.0f / (1.0f + expf(-nrm));
        us[e * 3 + 0] *= gate;
        us[e * 3 + 1] *= gate;
        us[e * 3 + 2] *= gate;
    }
    __syncthreads();

    if (tid < 64) {
        float acc = 0.0f;
        #pragma unroll
        for (int j = 0; j < 256; j++) acc += ts[j] * F0w2[j * D0 + tid];
        f0b[(size_t)node * D0 + tid] += acc;
    } else if (tid < 112) {
        int idx = tid - 64, f = idx / 3, m = idx % 3;
        float acc = 0.0f;
        #pragma unroll
        for (int e = 0; e < 64; e++) acc += us[e * 3 + m] * F1w2[e * D1 + f];
        f1b[(size_t)node * D13 + idx] += acc;
    }
}

// ---------------- final concat ----------------
__global__ void concat_kernel(const float* __restrict__ f0b,
                              const float* __restrict__ f1b,
                              float* __restrict__ out) {
    int i = blockIdx.x * blockDim.x + threadIdx.x;
    if (i >= BB * NN * (D0 + D13)) return;
    int node = i / (D0 + D13), c = i % (D0 + D13);
    out[i] = (c < D0) ? f0b[(size_t)node * D0 + c]
                      : f1b[(size_t)node * D13 + (c - D0)];
}

extern "C" void kernel_launch(void* const* d_in, const int* in_sizes, int n_in,
                              void* d_out, int out_size, void* d_ws, size_t ws_size,
                              hipStream_t stream) {
    const float* f0     = (const float*)d_in[0];
    const float* f1     = (const float*)d_in[1];
    const float* coords = (const float*)d_in[2];
    const int*   nbr    = (const int*)d_in[3];
    const float* Wq0    = (const float*)d_in[4];
    const float* Wq1    = (const float*)d_in[5];
    const float* Wk00   = (const float*)d_in[6];
    const float* Wk10   = (const float*)d_in[7];
    const float* Wk01   = (const float*)d_in[8];
    const float* Wk11   = (const float*)d_in[9];
    const float* Wk11r  = (const float*)d_in[10];
    const float* Wv00   = (const float*)d_in[11];
    const float* Wv10   = (const float*)d_in[12];
    const float* Wv01   = (const float*)d_in[13];
    const float* Wv11   = (const float*)d_in[14];
    const float* Wv11r  = (const float*)d_in[15];
    const float* Rw1    = (const float*)d_in[16];
    const float* Rb1    = (const float*)d_in[17];
    const float* Rw20   = (const float*)d_in[18];
    const float* Rw21   = (const float*)d_in[19];
    const float* Wo0    = (const float*)d_in[20];
    const float* Wo1    = (const float*)d_in[21];
    const float* F0w1   = (const float*)d_in[22];
    const float* F0w2   = (const float*)d_in[23];
    const float* F1w1   = (const float*)d_in[24];
    const float* F1w2   = (const float*)d_in[25];
    float* out = (float*)d_out;

    int nodes = BB * NN;

    // workspace layout (~50 MB)
    float* wf = (float*)d_ws;
    float* f0b   = wf; wf += (size_t)nodes * D0;
    float* f1b   = wf; wf += (size_t)nodes * D13;
    float* g1b   = wf; wf += (size_t)nodes * D13;
    float* q0b   = wf; wf += (size_t)nodes * D0;
    float* q1b   = wf; wf += (size_t)nodes * D13;
    float* rhatb = wf; wf += (size_t)ETOT * 3;
    float* distb = wf; wf += (size_t)ETOT;
    unsigned short* wu = (unsigned short*)wf;
    unsigned short* g0H  = wu; wu += (size_t)nodes * D0;
    unsigned short* g0L  = wu; wu += (size_t)nodes * D0;
    unsigned short* g1mH = wu; wu += (size_t)nodes * D13;
    unsigned short* g1mL = wu; wu += (size_t)nodes * D13;
    unsigned short* d1H  = wu; wu += (size_t)ETOT * 16;
    unsigned short* d1L  = wu; wu += (size_t)ETOT * 16;
    unsigned short* rhH  = wu; wu += (size_t)ETOT * 16;
    unsigned short* rhL  = wu; wu += (size_t)ETOT * 16;
    unsigned short* B1H = wu; wu += 1536 * 8;
    unsigned short* B1L = wu; wu += 1536 * 8;
    unsigned short* B2H = wu; wu += 2048 * 8;
    unsigned short* B2L = wu; wu += 2048 * 8;
    unsigned short* R0H = wu; wu += 256 * 8;
    unsigned short* R0L = wu; wu += 256 * 8;
    unsigned short* R1H = wu; wu += 64 * 8;
    unsigned short* R1L = wu; wu += 64 * 8;

    geom_kernel<<<(ETOT + 255) / 256, 256, 0, stream>>>(coords, nbr, rhatb, distb);
    hipMemcpyAsync(f0b, f0, (size_t)nodes * D0 * sizeof(float),
                   hipMemcpyDeviceToDevice, stream);
    hipMemcpyAsync(f1b, f1, (size_t)nodes * D13 * sizeof(float),
                   hipMemcpyDeviceToDevice, stream);

    for (int l = 0; l < NLAYER; l++) {
        prenorm_q_kernel<<<nodes, 64, 0, stream>>>(
            f0b, f1b, Wq0 + l * D0 * D0, Wq1 + l * D1 * D1,
            g1b, q0b, q1b, g0H, g0L, g1mH, g1mL);
        prep_kernel<<<16, 256, 0, stream>>>(
            Wk00 + l * D0 * D0, Wk10 + l * D1 * D0,
            Wk01 + l * D0 * D1, Wk11 + l * D1 * D1, Wk11r + l * D1 * D1,
            Wv00 + l * D0 * D0, Wv10 + l * D1 * D0,
            Wv01 + l * D0 * D1, Wv11 + l * D1 * D1, Wv11r + l * D1 * D1,
            Rw20 + l * RHD * D0, Rw21 + l * RHD * D1,
            B1H, B1L, B2H, B2L, R0H, R0L, R1H, R1L);
        edge_prep_kernel<<<ETOT * 16 / 256, 256, 0, stream>>>(
            nbr, rhatb, distb, g1b, Rw1 + l * RHD, Rb1 + l * RHD,
            d1H, d1L, rhH, rhL);
        attn_fused_kernel<<<ETOT / 64, 128, 0, stream>>>(
            nbr, rhatb, q0b, q1b,
            g0H, g0L, g1mH, g1mL, d1H, d1L, rhH, rhL,
            B1H, B1L, B2H, B2L, R0H, R0L, R1H, R1L,
            Wo0 + l * D0 * D0, Wo1 + l * D1 * D1,
            f0b, f1b);
        ffn_kernel<<<nodes, 256, 0, stream>>>(
            F0w1 + l * D0 * 256, F0w2 + l * 256 * D0,
            F1w1 + l * D1 * 64, F1w2 + l * 64 * D1,
            f0b, f1b);
    }

    concat_kernel<<<(nodes * (D0 + D13) + 255) / 256, 256, 0, stream>>>(f0b, f1b, out);
}